// Round 1
// baseline (431.928 us; speedup 1.0000x reference)
//
#include <hip/hip_runtime.h>
#include <hip/hip_bf16.h>

typedef __attribute__((ext_vector_type(8))) short short8;
typedef __attribute__((ext_vector_type(4))) float f32x4;

#define NSEQ 8192
#define NQH 32
#define NKH 2
#define NG 16
#define ND 128
#define NM 511
#define MPAD 512
#define SM_SCALE 0.08838834764831845f

__device__ __forceinline__ unsigned short f2bf(float f) {
  unsigned int u = __builtin_bit_cast(unsigned int, f);
  u += 0x7fffu + ((u >> 16) & 1u);
  return (unsigned short)(u >> 16);
}

// ck[h][m][d] (row-major), cvT[h][d][m] (transposed so PV B-frags are contiguous)
__global__ __launch_bounds__(128)
void nsa_compress(const float* __restrict__ kin, const float* __restrict__ vin,
                  const float* __restrict__ weight, const float* __restrict__ pe,
                  unsigned short* __restrict__ ck, unsigned short* __restrict__ cvT)
{
  const int h = (int)blockIdx.x >> 9;        // MPAD = 512
  const int m = (int)blockIdx.x & (MPAD - 1);
  const int d = (int)threadIdx.x;
  if (m >= NM) {  // zero the pad row (ws is poisoned 0xAA before every launch)
    ck[((size_t)h*MPAD + m)*ND + d] = 0;
    cvT[((size_t)h*ND + d)*MPAD + m] = 0;
    return;
  }
  float wsum = 0.f;
  #pragma unroll
  for (int j = 0; j < 32; ++j) wsum += weight[j];
  wsum = fmaxf(wsum, 1e-6f);
  const float inv = 1.0f / wsum;
  float ak = 0.f, av = 0.f;
  const int base = (m*16)*NKH*ND + h*ND + d;
  #pragma unroll
  for (int j = 0; j < 32; ++j) {
    const float w = weight[j];
    const float p = pe[j*ND + d];
    ak += w * (kin[base + j*NKH*ND] + p);
    av += w * (vin[base + j*NKH*ND] + p);
  }
  ck[((size_t)h*MPAD + m)*ND + d]  = f2bf(ak * inv);
  cvT[((size_t)h*ND + d)*MPAD + m] = f2bf(av * inv);
}

// One wave = 4 consecutive i's x 8 g's (two 16-row MFMA A-tiles).
// Block = 4 waves: (w&1) -> g-half, (w>>1) -> i sub-tile. No __syncthreads.
__global__ __launch_bounds__(256)
void nsa_attn(const float* __restrict__ q,
              const unsigned short* __restrict__ ck,
              const unsigned short* __restrict__ cvT,
              float* __restrict__ out)
{
  __shared__ short p_lds[2][4][2][16][32];  // [dbuf][wave][tile][row][m] bf16
  const int tid = (int)threadIdx.x;
  const int w   = tid >> 6;
  const int l   = tid & 63;
  const int lq  = l >> 4;    // quarter-wave index (k-chunk / C-row group)
  const int lm  = l & 15;    // B-col / C-col index

  const int h  = (int)blockIdx.x & 1;
  const int ib = (int)blockIdx.x >> 1;
  const int i0 = ib*8 + (w >> 1)*4;
  const int gb = (w & 1)*8;

  // ---- Q -> bf16 A-fragments in registers (A: row = l&15, k = lq*8 + j) ----
  short8 qa[2][4];
  {
    const int ia = i0 + (lm >> 2);
    #pragma unroll
    for (int t = 0; t < 2; ++t) {
      const int qh = h*NG + gb + t*4 + (l & 3);
      const float* qp = q + ((size_t)ia*NQH + qh)*ND;
      #pragma unroll
      for (int kc = 0; kc < 4; ++kc) {
        const float4 f0 = *(const float4*)(qp + kc*32 + lq*8);
        const float4 f1 = *(const float4*)(qp + kc*32 + lq*8 + 4);
        short8 a;
        a[0] = (short)f2bf(f0.x); a[1] = (short)f2bf(f0.y);
        a[2] = (short)f2bf(f0.z); a[3] = (short)f2bf(f0.w);
        a[4] = (short)f2bf(f1.x); a[5] = (short)f2bf(f1.y);
        a[6] = (short)f2bf(f1.z); a[7] = (short)f2bf(f1.w);
        qa[t][kc] = a;
      }
    }
  }

  // In C/D layout, row = lq*4 + r  ->  i depends only on lq (same for all regs)
  const int i_row = i0 + lq;
  const int mmax  = (i_row >= 31) ? ((i_row - 31) >> 4) : -1;
  const int mlimw = ((i0 + 3) >= 31) ? ((i0 + 3 - 31) >> 4) : -1;
  const int nt    = (mlimw >= 0) ? ((mlimw + 32) >> 5) : 0;

  f32x4 accO[2][8];
  #pragma unroll
  for (int t = 0; t < 2; ++t)
    #pragma unroll
    for (int dt = 0; dt < 8; ++dt) accO[t][dt] = (f32x4){0.f, 0.f, 0.f, 0.f};
  float mx[2][4], sm[2][4];
  #pragma unroll
  for (int t = 0; t < 2; ++t)
    #pragma unroll
    for (int r = 0; r < 4; ++r) { mx[t][r] = -1e30f; sm[t][r] = 0.f; }

  const unsigned short* ckh = ck  + (size_t)h*MPAD*ND;
  const unsigned short* cvh = cvT + (size_t)h*ND*MPAD;

  for (int mt = 0; mt < nt; ++mt) {
    const int m0 = mt*32;
    // ---- S = Q * CK^T for 32 queries x 32 m ----
    f32x4 accS[2][2];
    #pragma unroll
    for (int t = 0; t < 2; ++t)
      #pragma unroll
      for (int c = 0; c < 2; ++c) accS[t][c] = (f32x4){0.f, 0.f, 0.f, 0.f};
    #pragma unroll
    for (int kc = 0; kc < 4; ++kc) {
      const short8 b0 = *(const short8*)(ckh + (size_t)(m0 + lm)*ND      + kc*32 + lq*8);
      const short8 b1 = *(const short8*)(ckh + (size_t)(m0 + 16 + lm)*ND + kc*32 + lq*8);
      #pragma unroll
      for (int t = 0; t < 2; ++t) {
        accS[t][0] = __builtin_amdgcn_mfma_f32_16x16x32_bf16(qa[t][kc], b0, accS[t][0], 0, 0, 0);
        accS[t][1] = __builtin_amdgcn_mfma_f32_16x16x32_bf16(qa[t][kc], b1, accS[t][1], 0, 0, 0);
      }
    }
    // ---- online softmax (rows live on lanes with same lq; cols on lm) ----
    #pragma unroll
    for (int t = 0; t < 2; ++t) {
      float pm0[4], pm1[4];
      #pragma unroll
      for (int r = 0; r < 4; ++r) {
        const float s0 = accS[t][0][r]*SM_SCALE;
        const float s1 = accS[t][1][r]*SM_SCALE;
        pm0[r] = ((m0 + lm)      <= mmax) ? s0 : -1e30f;
        pm1[r] = ((m0 + 16 + lm) <= mmax) ? s1 : -1e30f;
      }
      #pragma unroll
      for (int r = 0; r < 4; ++r) {
        float t0 = fmaxf(pm0[r], pm1[r]);
        t0 = fmaxf(t0, __shfl_xor(t0, 1));
        t0 = fmaxf(t0, __shfl_xor(t0, 2));
        t0 = fmaxf(t0, __shfl_xor(t0, 4));
        t0 = fmaxf(t0, __shfl_xor(t0, 8));
        const float mnew = fmaxf(mx[t][r], t0);
        const float resc = __expf(mx[t][r] - mnew);
        mx[t][r] = mnew;
        const float p0 = __expf(pm0[r] - mnew);
        const float p1 = __expf(pm1[r] - mnew);
        float rs = p0 + p1;
        rs += __shfl_xor(rs, 1);
        rs += __shfl_xor(rs, 2);
        rs += __shfl_xor(rs, 4);
        rs += __shfl_xor(rs, 8);
        sm[t][r] = sm[t][r]*resc + rs;
        #pragma unroll
        for (int dt = 0; dt < 8; ++dt) accO[t][dt][r] *= resc;
        // C/D layout -> LDS (row = lq*4+r, col = m)
        p_lds[mt & 1][w][t][lq*4 + r][lm]      = (short)f2bf(p0);
        p_lds[mt & 1][w][t][lq*4 + r][16 + lm] = (short)f2bf(p1);
      }
    }
    // order cross-lane LDS write -> read within the wave
    asm volatile("s_waitcnt lgkmcnt(0)" ::: "memory");
    short8 pa[2];
    #pragma unroll
    for (int t = 0; t < 2; ++t)
      pa[t] = *(const short8*)(&p_lds[mt & 1][w][t][lm][lq*8]);
    // ---- O += P * CV ----
    #pragma unroll
    for (int dt = 0; dt < 8; ++dt) {
      const short8 bv = *(const short8*)(cvh + (size_t)(dt*16 + lm)*MPAD + m0 + lq*8);
      #pragma unroll
      for (int t = 0; t < 2; ++t)
        accO[t][dt] = __builtin_amdgcn_mfma_f32_16x16x32_bf16(pa[t], bv, accO[t][dt], 0, 0, 0);
    }
  }

  // ---- epilogue: normalize, zero invalid rows (i < 31) ----
  #pragma unroll
  for (int t = 0; t < 2; ++t) {
    #pragma unroll
    for (int r = 0; r < 4; ++r) {
      const float rinv = (mmax >= 0) ? (1.0f / sm[t][r]) : 0.0f;
      const int qh = h*NG + gb + t*4 + r;
      float* op = out + ((size_t)i_row*NQH + qh)*ND;
      #pragma unroll
      for (int dt = 0; dt < 8; ++dt)
        op[dt*16 + lm] = accO[t][dt][r] * rinv;
    }
  }
}

extern "C" void kernel_launch(void* const* d_in, const int* in_sizes, int n_in,
                              void* d_out, int out_size, void* d_ws, size_t ws_size,
                              hipStream_t stream)
{
  const float* q  = (const float*)d_in[0];
  const float* k  = (const float*)d_in[1];
  const float* v  = (const float*)d_in[2];
  const float* wt = (const float*)d_in[3];
  const float* pe = (const float*)d_in[4];
  float* outp = (float*)d_out;
  unsigned short* ck  = (unsigned short*)d_ws;                 // 2*512*128*2 B
  unsigned short* cvT = ck + (size_t)NKH*MPAD*ND;              // 2*128*512*2 B
  nsa_compress<<<NKH*MPAD, 128, 0, stream>>>(k, v, wt, pe, ck, cvT);
  nsa_attn<<<2048, 256, 0, stream>>>(q, ck, cvT, outp);
}

// Round 5
// 396.291 us; speedup vs baseline: 1.0899x; 1.0899x over previous
//
#include <hip/hip_runtime.h>
#include <hip/hip_bf16.h>

typedef __attribute__((ext_vector_type(8))) short short8;
typedef __attribute__((ext_vector_type(4))) float f32x4;
typedef __attribute__((ext_vector_type(16))) float f32x16;

#define NSEQ 8192
#define NQH 32
#define NKH 2
#define NG 16
#define ND 128
#define NM 511
#define MPAD 512
#define SM_SCALE 0.08838834764831845f
#define DEFER_THR 8.0f

__device__ __forceinline__ unsigned short f2bf(float f) {
  unsigned int u = __builtin_bit_cast(unsigned int, f);
  u += 0x7fffu + ((u >> 16) & 1u);
  return (unsigned short)(u >> 16);
}

__device__ __forceinline__ int cvtpk(float lo, float hi) {  // dst.lo16=bf16(lo), dst.hi16=bf16(hi)
  int r; asm("v_cvt_pk_bf16_f32 %0, %1, %2" : "=v"(r) : "v"(lo), "v"(hi)); return r;
}

__device__ __forceinline__ float swap_max(float x) {  // max(own, lane^32)
  return fmaxf(x, __shfl_xor(x, 32));
}

__device__ __forceinline__ float swap_add(float x) {  // own + lane^32
  return x + __shfl_xor(x, 32);
}

// ck[h][m][d] row-major bf16; cvT[h][d][m] bf16 (m-contiguous for PV A-frags).
// y[m][d] = (sum_j w[j]*x[16m+j][d] + pebias[d]) / wsum,  pebias = sum_j w[j]*pe[j][d]
__global__ __launch_bounds__(128)
void nsa_compress(const float* __restrict__ kin, const float* __restrict__ vin,
                  const float* __restrict__ wt, const float* __restrict__ pe,
                  unsigned short* __restrict__ ck, unsigned short* __restrict__ cvT)
{
  const int h  = (int)blockIdx.x >> 7;
  const int m0 = ((int)blockIdx.x & 127) * 4;
  const int d  = (int)threadIdx.x;

  float w[32]; float wsum = 0.f;
  #pragma unroll
  for (int j = 0; j < 32; ++j) { w[j] = wt[j]; wsum += w[j]; }
  const float inv = 1.0f / fmaxf(wsum, 1e-6f);
  float pb = 0.f;
  #pragma unroll
  for (int j = 0; j < 32; ++j) pb += w[j] * pe[j*ND + d];

  unsigned short rk[4], rv[4];
  #pragma unroll
  for (int mm = 0; mm < 4; ++mm) {
    const int m = m0 + mm;
    float sk = 0.f, sv = 0.f;
    if (m < NM) {
      const int rb = m * 16;
      #pragma unroll
      for (int j = 0; j < 32; ++j) {
        const size_t off = ((size_t)(rb + j)*NKH + h)*ND + d;
        sk += w[j] * kin[off];
        sv += w[j] * vin[off];
      }
      rk[mm] = f2bf((sk + pb) * inv);
      rv[mm] = f2bf((sv + pb) * inv);
    } else { rk[mm] = 0; rv[mm] = 0; }
    ck[((size_t)h*MPAD + m)*ND + d] = rk[mm];
  }
  ushort4 pv; pv.x = rv[0]; pv.y = rv[1]; pv.z = rv[2]; pv.w = rv[3];
  *(ushort4*)(cvT + ((size_t)h*ND + d)*MPAD + m0) = pv;
}

// 4 waves/block. Wave w: 32 query cols = 2 i's (i_base+2w, +1) x 16 g's, head h.
// Swapped QK: S^T[m][q] = mfma32x32x16(A=K rows, B=Q cols); softmax lane-local;
// P -> B-frag via cvt_pk + shfl_xor(32); O^T accumulated; LDS-transposed store.
__global__ __launch_bounds__(256, 2)
void nsa_attn(const float* __restrict__ q,
              const unsigned short* __restrict__ ck,
              const unsigned short* __restrict__ cvT,
              float* __restrict__ out)
{
  __shared__ __align__(16) char smem[32768];
  const int tid = (int)threadIdx.x;
  const int w = tid >> 6, l = tid & 63;
  const int lo5 = l & 31, hi = l >> 5;
  const int h = (int)blockIdx.x & 1;
  const int ib = 1023 - ((int)blockIdx.x >> 1);   // longest work launches first
  const int i_base = ib * 8;

  // ---- stage Q (8 i x 16 g x 128 d) into LDS as scaled bf16, XOR-swizzled ----
  {
    const int r = tid >> 1, half = tid & 1;
    const float* qp = q + ((size_t)(i_base + (r >> 4))*NQH + h*NG + (r & 15))*ND + half*64;
    char* base = smem + r*256;
    #pragma unroll
    for (int jj = 0; jj < 8; ++jj) {
      const float4 f0 = *(const float4*)(qp + jj*8);
      const float4 f1 = *(const float4*)(qp + jj*8 + 4);
      short8 a;
      a[0] = (short)f2bf(f0.x*SM_SCALE); a[1] = (short)f2bf(f0.y*SM_SCALE);
      a[2] = (short)f2bf(f0.z*SM_SCALE); a[3] = (short)f2bf(f0.w*SM_SCALE);
      a[4] = (short)f2bf(f1.x*SM_SCALE); a[5] = (short)f2bf(f1.y*SM_SCALE);
      a[6] = (short)f2bf(f1.z*SM_SCALE); a[7] = (short)f2bf(f1.w*SM_SCALE);
      *(short8*)(base + ((half*128 + jj*16) ^ ((r & 7) << 4))) = a;
    }
  }
  __syncthreads();

  // ---- Q B-frags to registers: col q = lo5, k(d) = kc*16 + hi*8 + j ----
  short8 qf[8];
  {
    const int r = w*32 + lo5;
    const char* base = smem + r*256;
    #pragma unroll
    for (int kc = 0; kc < 8; ++kc)
      qf[kc] = *(const short8*)(base + ((kc*32 + hi*16) ^ ((r & 7) << 4)));
  }

  const int ilo    = i_base + 2*w;
  const int i_lane = ilo + (lo5 >> 4);
  const int mmax    = (i_lane >= 31) ? ((i_lane - 31) >> 4) : -1;
  const int mmax_lo = (ilo    >= 31) ? ((ilo    - 31) >> 4) : -1;
  const int mlim    = (ilo + 1 >= 31) ? ((ilo + 1 - 31) >> 4) : -1;
  const int nt      = (mlim >= 0) ? ((mlim + 32) >> 5) : 0;

  f32x16 o[4];
  #pragma unroll
  for (int dt = 0; dt < 4; ++dt)
    #pragma unroll
    for (int rg = 0; rg < 16; ++rg) o[dt][rg] = 0.f;
  float mx = -1e30f, sml = 0.f;

  const unsigned short* ckh = ck  + (size_t)h*MPAD*ND;
  const unsigned short* cvh = cvT + (size_t)h*ND*MPAD;
  const unsigned short* kbase = ckh + (size_t)lo5*ND + hi*8;
  const unsigned short* vbase = cvh + (size_t)lo5*MPAD + hi*8;

  for (int mt = 0; mt < nt; ++mt) {
    const int m0 = mt * 32;

    // ---- S^T = K * Q : A = ck rows (m0+lo5), B = Q cols ----
    short8 kf[8];
    const unsigned short* kp = kbase + (size_t)m0*ND;
    #pragma unroll
    for (int kc = 0; kc < 8; ++kc) kf[kc] = *(const short8*)(kp + kc*16);
    f32x16 s;
    #pragma unroll
    for (int rg = 0; rg < 16; ++rg) s[rg] = 0.f;
    #pragma unroll
    for (int kc = 0; kc < 8; ++kc)
      s = __builtin_amdgcn_mfma_f32_32x32x16_bf16(kf[kc], qf[kc], s, 0, 0, 0);

    // ---- mask (boundary tiles only; wave-uniform branch) ----
    float sv[16];
    #pragma unroll
    for (int rg = 0; rg < 16; ++rg) sv[rg] = s[rg];
    if (m0 + 31 > mmax_lo) {
      #pragma unroll
      for (int rg = 0; rg < 16; ++rg) {
        const int mr = m0 + (rg & 3) + 8*(rg >> 2) + 4*hi;
        sv[rg] = (mr <= mmax) ? sv[rg] : -1e30f;
      }
    }

    // ---- row max (15 fmax tree + shfl swap), defer-max rescale ----
    float t0 = fmaxf(sv[0], sv[1]),   t1 = fmaxf(sv[2], sv[3]);
    float t2 = fmaxf(sv[4], sv[5]),   t3 = fmaxf(sv[6], sv[7]);
    float t4 = fmaxf(sv[8], sv[9]),   t5 = fmaxf(sv[10], sv[11]);
    float t6 = fmaxf(sv[12], sv[13]), t7 = fmaxf(sv[14], sv[15]);
    t0 = fmaxf(t0, t1); t2 = fmaxf(t2, t3); t4 = fmaxf(t4, t5); t6 = fmaxf(t6, t7);
    float cand = swap_max(fmaxf(fmaxf(t0, t2), fmaxf(t4, t6)));
    if (__any(cand > mx + DEFER_THR)) {
      const float nmx = fmaxf(mx, cand);
      const float resc = __expf(mx - nmx);
      mx = nmx;
      sml *= resc;
      #pragma unroll
      for (int dt = 0; dt < 4; ++dt)
        #pragma unroll
        for (int rg = 0; rg < 16; ++rg) o[dt][rg] *= resc;
    }

    // ---- p = exp(s - mx); lane-local partial sum ----
    float p[16];
    #pragma unroll
    for (int rg = 0; rg < 16; ++rg) p[rg] = __expf(sv[rg] - mx);
    float s0 = (p[0]+p[1]) + (p[2]+p[3]),   s1 = (p[4]+p[5]) + (p[6]+p[7]);
    float s2 = (p[8]+p[9]) + (p[10]+p[11]), s3 = (p[12]+p[13]) + (p[14]+p[15]);
    sml += (s0 + s1) + (s2 + s3);

    // ---- P -> B-frag dwords (k = hi*8 + j per 16-m chunk) via shfl_xor(32) ----
    // lane(hi=0) holds m {0-3,8-11}(+base); needs dw: (m0,m1)(m2,m3)(m4,m5)(m6,m7)
    // lane(hi=1) holds m {4-7,12-15}; needs dw: (m8,m9)(m10,m11)(m12,m13)(m14,m15)
    int d0 = cvtpk(p[0], p[1]),   d1 = cvtpk(p[2], p[3]);
    int d2 = cvtpk(p[4], p[5]),   d3 = cvtpk(p[6], p[7]);
    int d4 = cvtpk(p[8], p[9]),   d5 = cvtpk(p[10], p[11]);
    int d6 = cvtpk(p[12], p[13]), d7 = cvtpk(p[14], p[15]);
    const int x0 = __shfl_xor(d0, 32), x1 = __shfl_xor(d1, 32);
    const int x2 = __shfl_xor(d2, 32), x3 = __shfl_xor(d3, 32);
    const int x4 = __shfl_xor(d4, 32), x5 = __shfl_xor(d5, 32);
    const int x6 = __shfl_xor(d6, 32), x7 = __shfl_xor(d7, 32);
    const bool hib = (hi != 0);
    int4 pf0i = { hib ? x2 : d0, hib ? x3 : d1, hib ? d2 : x0, hib ? d3 : x1 };
    int4 pf1i = { hib ? x6 : d4, hib ? x7 : d5, hib ? d6 : x4, hib ? d7 : x5 };
    const short8 pf0 = __builtin_bit_cast(short8, pf0i);
    const short8 pf1 = __builtin_bit_cast(short8, pf1i);

    // ---- O^T += V^T * P : A = cvT rows (d), B = P cols (q) ----
    #pragma unroll
    for (int dt = 0; dt < 4; ++dt) {
      const unsigned short* vp = vbase + (size_t)dt*32*MPAD + m0;
      const short8 vf0 = *(const short8*)(vp);
      const short8 vf1 = *(const short8*)(vp + 16);
      o[dt] = __builtin_amdgcn_mfma_f32_32x32x16_bf16(vf0, pf0, o[dt], 0, 0, 0);
      o[dt] = __builtin_amdgcn_mfma_f32_32x32x16_bf16(vf1, pf1, o[dt], 0, 0, 0);
    }
  }

  // ---- epilogue: normalize, scalar-b32 LDS transpose (stride 33, per-wave
  // region, 4B ops => no alignment hazard, banks (q+d') => conflict-free) ----
  const float sfull = swap_add(sml);
  const float rinv = (mmax >= 0 && sfull > 0.f) ? 1.0f / sfull : 0.f;

  float* T = (float*)(smem + w*8192);   // this wave's Q rows are dead now
  const int q2 = l >> 1, xh = l & 1;
  float* op = out + ((size_t)(i_base + 2*w + (q2 >> 4))*NQH + h*NG + (q2 & 15))*ND;
  #pragma unroll
  for (int dt = 0; dt < 4; ++dt) {
    #pragma unroll
    for (int rg = 0; rg < 16; ++rg) {
      const int dp = (rg & 3) + 8*(rg >> 2) + 4*hi;   // d' within this dt block
      T[lo5*33 + dp] = o[dt][rg] * rinv;
    }
    asm volatile("s_waitcnt lgkmcnt(0)" ::: "memory");
    __builtin_amdgcn_sched_barrier(0);
    #pragma unroll
    for (int cc = 0; cc < 4; ++cc) {
      float4 vv;
      vv.x = T[q2*33 + xh*16 + cc*4 + 0];
      vv.y = T[q2*33 + xh*16 + cc*4 + 1];
      vv.z = T[q2*33 + xh*16 + cc*4 + 2];
      vv.w = T[q2*33 + xh*16 + cc*4 + 3];
      *(float4*)(op + dt*32 + xh*16 + cc*4) = vv;
    }
    asm volatile("s_waitcnt lgkmcnt(0)" ::: "memory");  // reads done before next dt reuses T
    __builtin_amdgcn_sched_barrier(0);
  }
}

extern "C" void kernel_launch(void* const* d_in, const int* in_sizes, int n_in,
                              void* d_out, int out_size, void* d_ws, size_t ws_size,
                              hipStream_t stream)
{
  const float* q  = (const float*)d_in[0];
  const float* k  = (const float*)d_in[1];
  const float* v  = (const float*)d_in[2];
  const float* wt = (const float*)d_in[3];
  const float* pe = (const float*)d_in[4];
  float* outp = (float*)d_out;
  unsigned short* ck  = (unsigned short*)d_ws;            // 2*512*128*2 B
  unsigned short* cvT = ck + (size_t)NKH*MPAD*ND;         // 2*128*512*2 B
  nsa_compress<<<256, 128, 0, stream>>>(k, v, wt, pe, ck, cvT);
  nsa_attn<<<2048, 256, 0, stream>>>(q, ck, cvT, outp);
}